// Round 7
// baseline (787.951 us; speedup 1.0000x reference)
//
#include <hip/hip_runtime.h>
#include <stdint.h>

#define T_SEQ 2048
#define D_DIM 512
#define NEXP 8

typedef short bf16x8 __attribute__((ext_vector_type(8)));
typedef float floatx4 __attribute__((ext_vector_type(4)));

__device__ __forceinline__ unsigned short f2bf(float f) {
  union { float f; unsigned u; } v; v.f = f;
  return (unsigned short)((v.u + 0x7fffu + ((v.u >> 16) & 1u)) >> 16);
}

// async global->LDS, 16B per lane. ldst must be wave-uniform base (HW adds lane*16).
__device__ __forceinline__ void gll16(const void* gsrc, void* ldst) {
  __builtin_amdgcn_global_load_lds(
      (const __attribute__((address_space(1))) unsigned int*)gsrc,
      (__attribute__((address_space(3))) unsigned int*)ldst, 16, 0, 0);
}

// ---------- prepass 1: K fp32 -> bf16, XOR-swizzle baked into global layout ----------
__global__ __launch_bounds__(256) void prep_k(const float* __restrict__ K,
                                              unsigned short* __restrict__ kws) {
  int idx = blockIdx.x * 256 + threadIdx.x;
  int r = idx >> 6;
  int c = idx & 63;
  const float4* src = (const float4*)(K + ((long)r << 9) + (c << 3));
  float4 a = src[0], b = src[1];
  bf16x8 v;
  v[0]=f2bf(a.x); v[1]=f2bf(a.y); v[2]=f2bf(a.z); v[3]=f2bf(a.w);
  v[4]=f2bf(b.x); v[5]=f2bf(b.y); v[6]=f2bf(b.z); v[7]=f2bf(b.w);
  int pos = (c ^ (r & 7)) << 4;
  *(bf16x8*)((char*)kws + ((long)r << 10) + pos) = v;
}

// ---------- prepass 2: V fp32 -> V^T bf16 [bh][d][k], swizzle baked ----------
__global__ __launch_bounds__(256) void prep_vt(const float* __restrict__ V,
                                               unsigned short* __restrict__ vt) {
  __shared__ unsigned short tile[64][72];
  int bid = blockIdx.x;
  int bh = bid >> 8;
  int kt = (bid >> 3) & 31;
  int dt = bid & 7;
  int k0 = kt << 6, d0 = dt << 6;
  int tid = threadIdx.x;
  {
    int kl = tid >> 2, dc = (tid & 3) << 4;
    const float4* src = (const float4*)(V + ((long)(bh * T_SEQ + k0 + kl) << 9) + d0 + dc);
#pragma unroll
    for (int i = 0; i < 4; ++i) {
      float4 a = src[i];
      tile[kl][dc + 4*i + 0] = f2bf(a.x);
      tile[kl][dc + 4*i + 1] = f2bf(a.y);
      tile[kl][dc + 4*i + 2] = f2bf(a.z);
      tile[kl][dc + 4*i + 3] = f2bf(a.w);
    }
  }
  __syncthreads();
  {
    int dl = tid >> 2, kc = (tid & 3) << 4;
    int d = d0 + dl;
    int swz = ((d ^ (d >> 2)) & 3) << 4;
    long rowbase = (long)(bh * 512 + d) << 12;
#pragma unroll
    for (int m = 0; m < 2; ++m) {
      bf16x8 v;
#pragma unroll
      for (int j = 0; j < 8; ++j) v[j] = tile[kc + 8*m + j][dl];
      int ks = k0 + kc + 8*m;
      int pos = ((ks >> 5) << 6) + ((((ks & 31) << 1)) ^ swz);
      *(bf16x8*)((char*)vt + rowbase + pos) = v;
    }
  }
}

// ---------- main flash-attention kernel (software-pipelined) ----------
// grid 256: bid&15 = head, bid>>4 = q-tile. 8 waves x 16 q-rows.
// Pipeline: softmax(kt) -> [vmcnt+barA] -> QK(kt+1) || PV(kt) -> [barB] -> stage(kt+2).
// LDS: dbuf {K 32KB + VT 32KB} at 0/65536; P-bounce (stride 80) at 131072 (total 141312).
__global__ __launch_bounds__(512, 2) void attn_main(
    const float* __restrict__ Q, const float* __restrict__ route,
    const int* __restrict__ mask, const unsigned short* __restrict__ kws,
    const unsigned short* __restrict__ vtw, float* __restrict__ out) {
  __shared__ __align__(16) char lds[141312];
  const int tid = threadIdx.x;
  const int wq = tid >> 6;
  const int lane = tid & 63;
  const int lq = lane & 15;
  const int g = lane >> 4;
  const int bh = blockIdx.x & 15;
  const int qb = blockIdx.x >> 4;
  const int qw = qb * 128 + wq * 16;
  const int b = bh >> 3;

  float g8[NEXP];
#pragma unroll
  for (int e = 0; e < NEXP; ++e) g8[e] = route[b * NEXP + e];

  // Q fragments: lane holds row qw+lq, d = 32t + 8g + i ; gate*0.125 folded in.
  bf16x8 qa[16];
  {
    const float* qrow = Q + ((long)(bh * T_SEQ + qw + lq) << 9) + g * 8;
#pragma unroll
    for (int t = 0; t < 16; ++t) {
      const float4* p = (const float4*)(qrow + t * 32);
      float4 a = p[0], c = p[1];
      float sc = g8[t >> 1] * 0.125f;
      qa[t][0]=f2bf(a.x*sc); qa[t][1]=f2bf(a.y*sc); qa[t][2]=f2bf(a.z*sc); qa[t][3]=f2bf(a.w*sc);
      qa[t][4]=f2bf(c.x*sc); qa[t][5]=f2bf(c.y*sc); qa[t][6]=f2bf(c.z*sc); qa[t][7]=f2bf(c.w*sc);
    }
  }

  floatx4 acc[32];
#pragma unroll
  for (int n = 0; n < 32; ++n) acc[n] = 0.f;
  float mrun[4] = {-3e38f, -3e38f, -3e38f, -3e38f};
  float lrun[4] = {0.f, 0.f, 0.f, 0.f};

  const char* kbase = (const char*)kws + ((long)bh << 21);
  const char* vbase = (const char*)vtw + ((long)bh << 21);
  const int swzK = (lq & 7) << 4;
  const int swzA = ((lq ^ (lq >> 2)) & 3) << 4;
  char* pbase = lds + 131072 + wq * 1280;      // 16 rows x 80B per wave

#define STAGE(buf, K0)                                                          \
  {                                                                             \
    char* kb_ = lds + (buf) * 65536;                                            \
    char* vb_ = kb_ + 32768;                                                    \
    _Pragma("unroll")                                                           \
    for (int r = 0; r < 4; ++r) {                                               \
      int row = 4 * wq + r;                                                     \
      gll16(kbase + ((long)((K0) + row) << 10) + lane * 16, kb_ + row * 1024);  \
    }                                                                           \
    _Pragma("unroll")                                                           \
    for (int r = 0; r < 4; ++r) {                                               \
      int dr0 = 64 * wq + 16 * r;                                               \
      gll16(vbase + ((long)(dr0 + (lane >> 2)) << 12) + (K0) * 2 + (lane & 3) * 16, \
            vb_ + dr0 * 64);                                                    \
    }                                                                           \
  }

#define QK16(KB, S0, S1)                                                        \
  _Pragma("unroll")                                                             \
  for (int t = 0; t < 16; ++t) {                                                \
    int off = (t * 64 + g * 16) ^ swzK;                                         \
    bf16x8 kf0 = *(const bf16x8*)((KB) + lq * 1024 + off);                      \
    bf16x8 kf1 = *(const bf16x8*)((KB) + (16 + lq) * 1024 + off);               \
    S0 = __builtin_amdgcn_mfma_f32_16x16x32_bf16(qa[t], kf0, S0, 0, 0, 0);      \
    S1 = __builtin_amdgcn_mfma_f32_16x16x32_bf16(qa[t], kf1, S1, 0, 0, 0);      \
  }

#define MASKLOAD(K0, M0, M1)                                                    \
  _Pragma("unroll")                                                             \
  for (int j = 0; j < 4; ++j) {                                                 \
    long mr = (long)(qw + 4 * g + j) * T_SEQ + (K0);                            \
    M0[j] = mask[mr + lq];                                                      \
    M1[j] = mask[mr + 16 + lq];                                                 \
  }

  // ---- prologue: stage(0); QK(0); stage(1) ----
  STAGE(0, 0)
  int mvA0[4], mvA1[4], mvB0[4], mvB1[4];
  MASKLOAD(0, mvA0, mvA1)
  asm volatile("s_waitcnt vmcnt(0)" ::: "memory");
  __syncthreads();
  floatx4 sA0 = 0.f, sA1 = 0.f;
  QK16(lds, sA0, sA1)                      // tile 0 from buf0
  STAGE(1, 32)                             // -> buf1

  for (int kt = 0; kt < T_SEQ / 32; ++kt) {
    const int cur = kt & 1;
    char* kb_next = lds + (cur ^ 1) * 65536;
    char* vb_cur  = lds + cur * 65536 + 32768;

    // ---- 1. softmax(kt) on sA (fp32, defer-max THR=8) ----
    float tmv[4];
    int grow = 0;
#pragma unroll
    for (int j = 0; j < 4; ++j) {
      if (mvA0[j]) sA0[j] = -3e38f;
      if (mvA1[j]) sA1[j] = -3e38f;
      float tm = fmaxf(sA0[j], sA1[j]);
      tm = fmaxf(tm, __shfl_xor(tm, 1));
      tm = fmaxf(tm, __shfl_xor(tm, 2));
      tm = fmaxf(tm, __shfl_xor(tm, 4));
      tm = fmaxf(tm, __shfl_xor(tm, 8));
      tmv[j] = tm;
      grow |= (tm > mrun[j] + 8.0f) ? 1 : 0;
    }
    if (__any(grow)) {
      float al[4];
#pragma unroll
      for (int j = 0; j < 4; ++j) {
        float mn = fmaxf(mrun[j], tmv[j]);
        al[j] = __expf(mrun[j] - mn);
        mrun[j] = mn;
        lrun[j] *= al[j];
      }
#pragma unroll
      for (int n = 0; n < 32; ++n) {
#pragma unroll
        for (int j = 0; j < 4; ++j) acc[n][j] *= al[j];
      }
    }
#pragma unroll
    for (int j = 0; j < 4; ++j) {
      float p0 = __expf(sA0[j] - mrun[j]);
      float p1 = __expf(sA1[j] - mrun[j]);
      sA0[j] = p0; sA1[j] = p1;
      float rs = p0 + p1;
      rs += __shfl_xor(rs, 1);
      rs += __shfl_xor(rs, 2);
      rs += __shfl_xor(rs, 4);
      rs += __shfl_xor(rs, 8);
      lrun[j] += rs;
    }
    // P -> wave-private LDS bounce
#pragma unroll
    for (int j = 0; j < 4; ++j) {
      int q = 4 * g + j;
      int swzP = ((q ^ (q >> 2)) & 3) << 4;
      *(unsigned short*)(pbase + q * 80 + ((2 * lq) ^ swzP))      = f2bf(sA0[j]);
      *(unsigned short*)(pbase + q * 80 + ((32 + 2 * lq) ^ swzP)) = f2bf(sA1[j]);
    }
    bf16x8 pa = *(const bf16x8*)(pbase + lq * 80 + ((16 * g) ^ swzA));

    // ---- 2+3. publish tile kt+1; QK(kt+1) (overlaps PV below) ----
    floatx4 sB0 = 0.f, sB1 = 0.f;
    if (kt < T_SEQ / 32 - 1) {
      asm volatile("s_waitcnt vmcnt(0)" ::: "memory");  // own stage(kt+1) done
      __syncthreads();                                   // all waves staged
      QK16(kb_next, sB0, sB1)
      MASKLOAD(kt * 32 + 32, mvB0, mvB1)
    }

    // ---- 4. PV(kt) ----
#pragma unroll
    for (int n = 0; n < 32; ++n) {
      int d = 16 * n + lq;
      int swzV = ((d ^ (d >> 2)) & 3) << 4;
      bf16x8 vb8 = *(const bf16x8*)(vb_cur + d * 64 + ((16 * g) ^ swzV));
      acc[n] = __builtin_amdgcn_mfma_f32_16x16x32_bf16(pa, vb8, acc[n], 0, 0, 0);
    }

    // ---- 6+7. all reads of buf(cur) done -> restage it with tile kt+2 ----
    if (kt < T_SEQ / 32 - 2) {
      __syncthreads();
      STAGE(cur, kt * 32 + 64)
    }

    // ---- swap pipeline registers ----
    sA0 = sB0; sA1 = sB1;
#pragma unroll
    for (int j = 0; j < 4; ++j) { mvA0[j] = mvB0[j]; mvA1[j] = mvB1[j]; }
  }

  // ---- epilogue: out = acc / l * gate ----
  float rl[4];
#pragma unroll
  for (int j = 0; j < 4; ++j) rl[j] = 1.0f / lrun[j];
#pragma unroll
  for (int n = 0; n < 32; ++n) {
    int d = 16 * n + lq;
    float gg = g8[n >> 2];
    float* op = out + ((long)(bh * T_SEQ + qw + 4 * g) << 9) + d;
#pragma unroll
    for (int j = 0; j < 4; ++j) op[(long)j << 9] = acc[n][j] * rl[j] * gg;
  }
}

extern "C" void kernel_launch(void* const* d_in, const int* in_sizes, int n_in,
                              void* d_out, int out_size, void* d_ws, size_t ws_size,
                              hipStream_t stream) {
  (void)in_sizes; (void)n_in; (void)out_size; (void)ws_size;
  const float* Q     = (const float*)d_in[0];
  const float* K     = (const float*)d_in[1];
  const float* V     = (const float*)d_in[2];
  const float* route = (const float*)d_in[3];
  const int*   mask  = (const int*)d_in[5];
  float* out = (float*)d_out;
  unsigned short* kws = (unsigned short*)d_ws;
  unsigned short* vtw = (unsigned short*)((char*)d_ws + 33554432);
  prep_k  <<<8192, 256, 0, stream>>>(K, kws);
  prep_vt <<<4096, 256, 0, stream>>>(V, vtw);
  attn_main<<<256, 512, 0, stream>>>(Q, route, mask, kws, vtw, out);
}